// Round 5
// baseline (16679.248 us; speedup 1.0000x reference)
//
#include <hip/hip_runtime.h>
#include <hip/hip_bf16.h>
#include <math.h>

// SequentialHRNN: T=512, B=64, IN=256, H=512, OUT=128, 3 layers.
// EXACT-fp32-emulation persistent kernel: every fp32 operand (h, W, x) is
// decomposed EXACTLY into 3 bf16 planes (hi + mid*2^-8 + lo*2^-16); 6 MFMA
// products per k-tile into scale-separated fp32 accumulators. Per-step
// arithmetic error ~1e-7 (fp32 class) -- required because the recurrence
// amplifies per-step noise by ~5e5 over 512 steps (measured: 2-plane bf16
// eps~1e-6 -> absmax 0.55; plain bf16 eps~4e-4 -> saturated 1.77).

#define T_STEPS 512
#define BATCH   64
#define IN_DIM  256
#define HID     512
#define OUT_DIM 128
#define BH      (BATCH * HID)     // one layer plane: 32768 elems
#define HPLANE  (3 * BH)          // one ping-pong buffer (per precision plane)

typedef unsigned short u16;
typedef unsigned short u16x8 __attribute__((ext_vector_type(8)));
typedef __bf16 bf16x8 __attribute__((ext_vector_type(8)));
typedef float f32x4 __attribute__((ext_vector_type(4)));

static __device__ __forceinline__ u16 f2bf(float f) {
  unsigned u = __builtin_bit_cast(unsigned, f);
  u += 0x7fffu + ((u >> 16) & 1u);   // round-to-nearest-even
  return (u16)(u >> 16);
}
static __device__ __forceinline__ float bf2f(u16 h) {
  return __builtin_bit_cast(float, (unsigned)h << 16);
}
static __device__ __forceinline__ bf16x8 asbf(u16x8 v) {
  return __builtin_bit_cast(bf16x8, v);
}
// exact 3-way split: f == hi + mid*2^-8 + lo*2^-16 (all residuals exact)
static __device__ __forceinline__ void split3(float f, u16& hi, u16& mid, u16& lo) {
  hi = f2bf(f);
  const float r1 = f - bf2f(hi);
  mid = f2bf(r1 * 256.f);
  const float r2 = r1 - bf2f(mid) * (1.f / 256.f);
  lo = f2bf(r2 * 65536.f);
}

// ---------------------------------------------------------------------------
// Grid: 96 blocks x 256 threads. Block wg: layer = wg>>5, c0 = (wg&31)*16.
// Wave wv (of 4) = M-tile (rows wv*16..+16); all waves share the 16 cols.
// LDS: weight slice in 3 bf16 planes, MFMA B-frag layout (<=147 KB), staged once.
// concat-K maps: L0: [x->Wbu0(256) | h0->Wrec0 | h1->Wtd0]   KT=40
//                L1: [h0->Wbu1 | h1->Wrec1 | h2->Wtd1]       KT=48
//                L2: [h1->Wbu2 | h2->Wrec2]                  KT=32
// ---------------------------------------------------------------------------
__global__ __launch_bounds__(256, 1) void hrnn_persistent(
    const float* __restrict__ x,
    const float* __restrict__ Wbu0, const float* __restrict__ Wtd0,
    const float* __restrict__ Wrec0, const float* __restrict__ b0,
    const float* __restrict__ Wbu1, const float* __restrict__ Wtd1,
    const float* __restrict__ Wrec1, const float* __restrict__ b1,
    const float* __restrict__ Wbu2, const float* __restrict__ Wrec2,
    const float* __restrict__ b2,
    float* __restrict__ top,        // [T][64][512] fp32 (d_out region 2)
    unsigned* __restrict__ bar,     // barrier words (zeroed each launch)
    u16* __restrict__ hbh,          // [2][3][64][512] bf16 hi plane (zeroed)
    u16* __restrict__ hbm,          // mid plane (x 2^8)
    u16* __restrict__ hbl)          // lo plane (x 2^16)
{
  __shared__ u16 lsBh[48 * 512];    // B-frag hi: lsBh[kt*512 + lane*8 + i]
  __shared__ u16 lsBm[48 * 512];    // B-frag mid (x 2^8)
  __shared__ u16 lsBl[48 * 512];    // B-frag lo  (x 2^16)

  const int wg    = blockIdx.x;
  const int layer = wg >> 5;
  const int c0    = (wg & 31) * 16;       // column base within layer
  const int tid   = threadIdx.x;
  const int wv    = tid >> 6;             // M-tile index 0..3
  const int lane  = tid & 63;
  const int KT    = (layer == 0) ? 40 : ((layer == 1) ? 48 : 32);

  // ---- one-time: stage weight slice (3 planes) into LDS, B-frag layout ----
  {
    const int cc = c0 + (lane & 15);
    for (int f = wv; f < KT; f += 4) {
      const int kk = f * 32 + ((lane >> 4) << 3);  // concat-k of first of 8
      const float* Wsrc; int kloc;
      if (layer == 0) {
        if (kk < 256)      { Wsrc = Wbu0;  kloc = kk; }
        else if (kk < 768) { Wsrc = Wrec0; kloc = kk - 256; }
        else               { Wsrc = Wtd0;  kloc = kk - 768; }
      } else if (layer == 1) {
        if (kk < 512)       { Wsrc = Wbu1;  kloc = kk; }
        else if (kk < 1024) { Wsrc = Wrec1; kloc = kk - 512; }
        else                { Wsrc = Wtd1;  kloc = kk - 1024; }
      } else {
        if (kk < 512) { Wsrc = Wbu2;  kloc = kk; }
        else          { Wsrc = Wrec2; kloc = kk - 512; }
      }
      u16* dh = &lsBh[f * 512 + lane * 8];
      u16* dm = &lsBm[f * 512 + lane * 8];
      u16* dl = &lsBl[f * 512 + lane * 8];
      #pragma unroll
      for (int i = 0; i < 8; ++i) {
        u16 h_, m_, l_;
        split3(Wsrc[(size_t)(kloc + i) * HID + cc], h_, m_, l_);
        dh[i] = h_; dm[i] = m_; dl[i] = l_;
      }
    }
  }
  const float* bl_ = (layer == 0) ? b0 : ((layer == 1) ? b1 : b2);
  const float bias = bl_[c0 + (lane & 15)];
  __syncthreads();

  const int arow    = wv * 16 + (lane & 15);   // A-operand batch row (0..63)
  const int lk      = (lane >> 4) << 3;        // A-operand k sub-offset
  const int rowbase = arow * HID + lk;
  unsigned* cnt = &bar[0];
  unsigned* gen = &bar[16];

  for (int t = 0; t < T_STEPS; ++t) {
    const u16* hrh = hbh + (t & 1) * HPLANE;
    const u16* hrm = hbm + (t & 1) * HPLANE;
    const u16* hrl = hbl + (t & 1) * HPLANE;
    u16* hwh       = hbh + ((t + 1) & 1) * HPLANE;
    u16* hwm       = hbm + ((t + 1) & 1) * HPLANE;
    u16* hwl       = hbl + ((t + 1) & 1) * HPLANE;

    f32x4 a0a = {0.f,0.f,0.f,0.f}, a0b = {0.f,0.f,0.f,0.f};   // hi*hi (even/odd kt)
    f32x4 a1  = {0.f,0.f,0.f,0.f};                            // scale 2^-8
    f32x4 a2  = {0.f,0.f,0.f,0.f};                            // scale 2^-16

#define MFMA6(kt, ah, am, al)                                                \
    {                                                                        \
      u16x8 bh = *(const u16x8*)&lsBh[(kt) * 512 + lane * 8];                \
      u16x8 bm = *(const u16x8*)&lsBm[(kt) * 512 + lane * 8];                \
      u16x8 bl = *(const u16x8*)&lsBl[(kt) * 512 + lane * 8];                \
      f32x4& a0 = ((kt) & 1) ? a0b : a0a;                                    \
      a0 = __builtin_amdgcn_mfma_f32_16x16x32_bf16(asbf(ah), asbf(bh), a0, 0, 0, 0); \
      a1 = __builtin_amdgcn_mfma_f32_16x16x32_bf16(asbf(ah), asbf(bm), a1, 0, 0, 0); \
      a2 = __builtin_amdgcn_mfma_f32_16x16x32_bf16(asbf(ah), asbf(bl), a2, 0, 0, 0); \
      a1 = __builtin_amdgcn_mfma_f32_16x16x32_bf16(asbf(am), asbf(bh), a1, 0, 0, 0); \
      a2 = __builtin_amdgcn_mfma_f32_16x16x32_bf16(asbf(am), asbf(bm), a2, 0, 0, 0); \
      a2 = __builtin_amdgcn_mfma_f32_16x16x32_bf16(asbf(al), asbf(bh), a2, 0, 0, 0); \
    }
#define KTILE_H(kt, off)                                                     \
    {                                                                        \
      u16x8 ah = *(const u16x8*)&hrh[(off) + rowbase];                       \
      u16x8 am = *(const u16x8*)&hrm[(off) + rowbase];                       \
      u16x8 al = *(const u16x8*)&hrl[(off) + rowbase];                       \
      MFMA6(kt, ah, am, al)                                                  \
    }

    if (layer == 0) {
      // k-tiles 0..7: x_t fp32 -> exact 3-plane split in-register
      const float* xr = x + ((size_t)t * BATCH + arow) * IN_DIM + lk;
      #pragma unroll 2
      for (int kt = 0; kt < 8; ++kt) {
        float4 p0 = *(const float4*)(xr + kt * 32);
        float4 p1 = *(const float4*)(xr + kt * 32 + 4);
        float pv[8] = {p0.x, p0.y, p0.z, p0.w, p1.x, p1.y, p1.z, p1.w};
        u16x8 ah, am, al;
        #pragma unroll
        for (int i = 0; i < 8; ++i) {
          u16 h_, m_, l_;
          split3(pv[i], h_, m_, l_);
          ah[i] = h_; am[i] = m_; al[i] = l_;
        }
        MFMA6(kt, ah, am, al)
      }
      // k-tiles 8..23: h0 (Wrec0), 24..39: h1 (Wtd0)
      #pragma unroll 4
      for (int kt = 8; kt < 40; ++kt) {
        const int off = (kt < 24) ? (kt - 8) * 32 : BH + (kt - 24) * 32;
        KTILE_H(kt, off)
      }
    } else if (layer == 1) {
      // 0..15: h0 (Wbu1), 16..31: h1 (Wrec1), 32..47: h2 (Wtd1)
      #pragma unroll 4
      for (int kt = 0; kt < 48; ++kt) {
        const int off = (kt < 16) ? kt * 32
                      : (kt < 32) ? BH + (kt - 16) * 32
                                  : 2 * BH + (kt - 32) * 32;
        KTILE_H(kt, off)
      }
    } else {
      // 0..15: h1 (Wbu2), 16..31: h2 (Wrec2)
      #pragma unroll 4
      for (int kt = 0; kt < 32; ++kt) {
        const int off = (kt < 16) ? BH + kt * 32 : 2 * BH + (kt - 16) * 32;
        KTILE_H(kt, off)
      }
    }
#undef KTILE_H
#undef MFMA6

    // combine scale-separated accumulators (exact pow-2 scales)
    const f32x4 tot = (a0a + a0b) + a1 * (1.f / 256.f) + a2 * (1.f / 65536.f);

    // epilogue: bias + fp64 tanh, write exact 3-plane hidden (+ fp32 top for L2)
    {
      const int ncol  = c0 + (lane & 15);
      const int mbase = wv * 16 + ((lane >> 4) << 2);
      #pragma unroll
      for (int r = 0; r < 4; ++r) {
        const float h = (float)tanh((double)(tot[r] + bias));
        u16 h_, m_, l_;
        split3(h, h_, m_, l_);
        const int idx = (layer * BATCH + mbase + r) * HID + ncol;
        hwh[idx] = h_; hwm[idx] = m_; hwl[idx] = l_;
        if (layer == 2)
          top[((size_t)t * BATCH + mbase + r) * HID + ncol] = h;
      }
    }

    // device barrier: 96 arrivals (release h writes -> LLC, acquire on exit)
    __syncthreads();
    if (tid == 0) {
      __threadfence();  // release: writeback XCD L2 so other XCDs see h
      const unsigned target = (unsigned)(t + 1) * 96u;
      const unsigned arr = atomicAdd(cnt, 1u);
      if (arr == target - 1u) {
        __hip_atomic_store(gen, (unsigned)(t + 1), __ATOMIC_RELAXED,
                           __HIP_MEMORY_SCOPE_AGENT);
      } else {
        while (__hip_atomic_load(gen, __ATOMIC_RELAXED,
                                 __HIP_MEMORY_SCOPE_AGENT) < (unsigned)(t + 1)) {
          __builtin_amdgcn_s_sleep(1);
        }
      }
      __threadfence();  // acquire: invalidate stale L1/L2 before next reads
    }
    __syncthreads();
  }
}

// ---------------------------------------------------------------------------
// Epilogue: pred[t*64+m][128] = top[t*64+m][512] @ Wc[512][128] + bc
// (non-recurrent: plain-bf16 Wc error ~3e-4 << threshold)
// ---------------------------------------------------------------------------
__global__ __launch_bounds__(256, 1) void hrnn_pred(
    const float* __restrict__ top, const float* __restrict__ Wc,
    const float* __restrict__ bc, float* __restrict__ pred)
{
  __shared__ u16 lsW[OUT_DIM * HID];  // [c][k swizzled], 128 KB
  const int tid = threadIdx.x;
  for (int idx = tid; idx < OUT_DIM * HID; idx += 256) {
    const int k = idx >> 7, c = idx & 127;           // Wc row-major [512][128]
    const int kg = k >> 3, ko = k & 7;
    lsW[c * HID + (((kg ^ (c & 7)) << 3) + ko)] = f2bf(Wc[idx]);
  }
  __syncthreads();

  const int t = blockIdx.x;
  const int wv = tid >> 6, lane = tid & 63;
  const int lk = (lane >> 4) << 3;
  f32x4 acc[8];
  #pragma unroll
  for (int nt = 0; nt < 8; ++nt) acc[nt] = (f32x4){0.f, 0.f, 0.f, 0.f};

  const float* ar = top + ((size_t)t * BATCH + wv * 16 + (lane & 15)) * HID + lk;
  #pragma unroll 4
  for (int kt = 0; kt < 16; ++kt) {
    float4 p0 = *(const float4*)(ar + kt * 32);
    float4 p1 = *(const float4*)(ar + kt * 32 + 4);
    u16x8 av;
    av[0]=f2bf(p0.x); av[1]=f2bf(p0.y); av[2]=f2bf(p0.z); av[3]=f2bf(p0.w);
    av[4]=f2bf(p1.x); av[5]=f2bf(p1.y); av[6]=f2bf(p1.z); av[7]=f2bf(p1.w);
    const bf16x8 a = asbf(av);
    const int kg = kt * 4 + (lane >> 4);
    #pragma unroll
    for (int nt = 0; nt < 8; ++nt) {
      const int c = nt * 16 + (lane & 15);
      u16x8 bv = *(const u16x8*)&lsW[c * HID + ((kg ^ (lane & 7)) << 3)];
      acc[nt] = __builtin_amdgcn_mfma_f32_16x16x32_bf16(a, asbf(bv), acc[nt], 0, 0, 0);
    }
  }
  #pragma unroll
  for (int nt = 0; nt < 8; ++nt) {
    const int col = nt * 16 + (lane & 15);
    const float bcv = bc[col];
    #pragma unroll
    for (int r = 0; r < 4; ++r) {
      const int m = wv * 16 + ((lane >> 4) << 2) + r;
      pred[((size_t)t * BATCH + m) * OUT_DIM + col] = acc[nt][r] + bcv;
    }
  }
}

extern "C" void kernel_launch(void* const* d_in, const int* in_sizes, int n_in,
                              void* d_out, int out_size, void* d_ws, size_t ws_size,
                              hipStream_t stream) {
  const float* x     = (const float*)d_in[0];
  const float* Wbu0  = (const float*)d_in[1];
  const float* Wtd0  = (const float*)d_in[2];
  const float* Wrec0 = (const float*)d_in[3];
  const float* b0    = (const float*)d_in[4];
  const float* Wbu1  = (const float*)d_in[5];
  const float* Wtd1  = (const float*)d_in[6];
  const float* Wrec1 = (const float*)d_in[7];
  const float* b1    = (const float*)d_in[8];
  const float* Wbu2  = (const float*)d_in[9];
  const float* Wrec2 = (const float*)d_in[10];
  const float* b2    = (const float*)d_in[11];
  const float* Wc    = (const float*)d_in[12];
  const float* bc    = (const float*)d_in[13];

  float* pred = (float*)d_out;
  float* top  = pred + (size_t)T_STEPS * BATCH * OUT_DIM;

  const size_t planes_bytes = (size_t)6 * HPLANE * sizeof(u16);  // 1.18 MB
  unsigned* bar = (unsigned*)d_ws;
  // h planes: prefer ws; fall back to pred region (16.8 MB, fully overwritten
  // by hrnn_pred afterwards) if ws is too small.
  char* planes = (ws_size >= 4096 + planes_bytes) ? ((char*)d_ws + 4096)
                                                  : (char*)d_out;
  u16* hbh = (u16*)planes;
  u16* hbm = (u16*)(planes + 2 * HPLANE * sizeof(u16));
  u16* hbl = (u16*)(planes + 4 * HPLANE * sizeof(u16));

  // zero barrier words + all three ping-pong hidden planes (h_init = 0)
  hipMemsetAsync(d_ws, 0, 4096, stream);
  hipMemsetAsync(planes, 0, planes_bytes, stream);

  hipLaunchKernelGGL(hrnn_persistent, dim3(96), dim3(256), 0, stream,
                     x, Wbu0, Wtd0, Wrec0, b0, Wbu1, Wtd1, Wrec1, b1,
                     Wbu2, Wrec2, b2, top, bar, hbh, hbm, hbl);
  hipLaunchKernelGGL(hrnn_pred, dim3(T_STEPS), dim3(256), 0, stream,
                     top, Wc, bc, pred);
}

// Round 6
// 15583.315 us; speedup vs baseline: 1.0703x; 1.0703x over previous
//
#include <hip/hip_runtime.h>
#include <hip/hip_bf16.h>
#include <math.h>

// SequentialHRNN: T=512, B=64, IN=256, H=512, OUT=128, 3 layers.
// EXACT-fp32-emulation persistent kernel (3-plane bf16 MFMA) — PASSED r5 at
// absmax 0.0576/0.0625. r6: keep arithmetic BIT-IDENTICAL; attack the ~28us/step
// sync cost: padded per-WG flag barrier (no 96-RMW serialization), nontemporal
// h/top stores (cheap wbl2), unroll 8 (more loads in flight at 1 wave/SIMD).

#define T_STEPS 512
#define BATCH   64
#define IN_DIM  256
#define HID     512
#define OUT_DIM 128
#define BH      (BATCH * HID)     // one layer plane: 32768 elems
#define HPLANE  (3 * BH)          // one ping-pong buffer (per precision plane)
#define NWG     96

typedef unsigned short u16;
typedef unsigned short u16x8 __attribute__((ext_vector_type(8)));
typedef __bf16 bf16x8 __attribute__((ext_vector_type(8)));
typedef float f32x4 __attribute__((ext_vector_type(4)));

static __device__ __forceinline__ u16 f2bf(float f) {
  unsigned u = __builtin_bit_cast(unsigned, f);
  u += 0x7fffu + ((u >> 16) & 1u);   // round-to-nearest-even
  return (u16)(u >> 16);
}
static __device__ __forceinline__ float bf2f(u16 h) {
  return __builtin_bit_cast(float, (unsigned)h << 16);
}
static __device__ __forceinline__ bf16x8 asbf(u16x8 v) {
  return __builtin_bit_cast(bf16x8, v);
}
// exact 3-way split: f == hi + mid*2^-8 + lo*2^-16 (all residuals exact)
static __device__ __forceinline__ void split3(float f, u16& hi, u16& mid, u16& lo) {
  hi = f2bf(f);
  const float r1 = f - bf2f(hi);
  mid = f2bf(r1 * 256.f);
  const float r2 = r1 - bf2f(mid) * (1.f / 256.f);
  lo = f2bf(r2 * 65536.f);
}

// ---------------------------------------------------------------------------
// Grid: 96 blocks x 256 threads. Block wg: layer = wg>>5, c0 = (wg&31)*16.
// Wave wv (of 4) = M-tile (rows wv*16..+16); all waves share the 16 cols.
// LDS: weight slice in 3 bf16 planes, MFMA B-frag layout (<=147 KB), staged once.
// concat-K maps: L0: [x->Wbu0(256) | h0->Wrec0 | h1->Wtd0]   KT=40
//                L1: [h0->Wbu1 | h1->Wrec1 | h2->Wtd1]       KT=48
//                L2: [h1->Wbu2 | h2->Wrec2]                  KT=32
// Barrier: per-WG 128B-padded flag words; release store + 96-thread poll.
// ---------------------------------------------------------------------------
__global__ __launch_bounds__(256, 1) void hrnn_persistent(
    const float* __restrict__ x,
    const float* __restrict__ Wbu0, const float* __restrict__ Wtd0,
    const float* __restrict__ Wrec0, const float* __restrict__ b0,
    const float* __restrict__ Wbu1, const float* __restrict__ Wtd1,
    const float* __restrict__ Wrec1, const float* __restrict__ b1,
    const float* __restrict__ Wbu2, const float* __restrict__ Wrec2,
    const float* __restrict__ b2,
    float* __restrict__ top,        // [T][64][512] fp32 (d_out region 2)
    unsigned* __restrict__ flags,   // 96 x 32 u32 padded flags (zeroed)
    u16* __restrict__ hbh,          // [2][3][64][512] bf16 hi plane (zeroed)
    u16* __restrict__ hbm,          // mid plane (x 2^8)
    u16* __restrict__ hbl)          // lo plane (x 2^16)
{
  __shared__ u16 lsBh[48 * 512];    // B-frag hi: lsBh[kt*512 + lane*8 + i]
  __shared__ u16 lsBm[48 * 512];    // B-frag mid (x 2^8)
  __shared__ u16 lsBl[48 * 512];    // B-frag lo  (x 2^16)

  const int wg    = blockIdx.x;
  const int layer = wg >> 5;
  const int c0    = (wg & 31) * 16;       // column base within layer
  const int tid   = threadIdx.x;
  const int wv    = tid >> 6;             // M-tile index 0..3
  const int lane  = tid & 63;
  const int KT    = (layer == 0) ? 40 : ((layer == 1) ? 48 : 32);

  // ---- one-time: stage weight slice (3 planes) into LDS, B-frag layout ----
  {
    const int cc = c0 + (lane & 15);
    for (int f = wv; f < KT; f += 4) {
      const int kk = f * 32 + ((lane >> 4) << 3);  // concat-k of first of 8
      const float* Wsrc; int kloc;
      if (layer == 0) {
        if (kk < 256)      { Wsrc = Wbu0;  kloc = kk; }
        else if (kk < 768) { Wsrc = Wrec0; kloc = kk - 256; }
        else               { Wsrc = Wtd0;  kloc = kk - 768; }
      } else if (layer == 1) {
        if (kk < 512)       { Wsrc = Wbu1;  kloc = kk; }
        else if (kk < 1024) { Wsrc = Wrec1; kloc = kk - 512; }
        else                { Wsrc = Wtd1;  kloc = kk - 1024; }
      } else {
        if (kk < 512) { Wsrc = Wbu2;  kloc = kk; }
        else          { Wsrc = Wrec2; kloc = kk - 512; }
      }
      u16* dh = &lsBh[f * 512 + lane * 8];
      u16* dm = &lsBm[f * 512 + lane * 8];
      u16* dl = &lsBl[f * 512 + lane * 8];
      #pragma unroll
      for (int i = 0; i < 8; ++i) {
        u16 h_, m_, l_;
        split3(Wsrc[(size_t)(kloc + i) * HID + cc], h_, m_, l_);
        dh[i] = h_; dm[i] = m_; dl[i] = l_;
      }
    }
  }
  const float* bl_ = (layer == 0) ? b0 : ((layer == 1) ? b1 : b2);
  const float bias = bl_[c0 + (lane & 15)];
  __syncthreads();

  const int arow    = wv * 16 + (lane & 15);   // A-operand batch row (0..63)
  const int lk      = (lane >> 4) << 3;        // A-operand k sub-offset
  const int rowbase = arow * HID + lk;

  for (int t = 0; t < T_STEPS; ++t) {
    const u16* hrh = hbh + (t & 1) * HPLANE;
    const u16* hrm = hbm + (t & 1) * HPLANE;
    const u16* hrl = hbl + (t & 1) * HPLANE;
    u16* hwh       = hbh + ((t + 1) & 1) * HPLANE;
    u16* hwm       = hbm + ((t + 1) & 1) * HPLANE;
    u16* hwl       = hbl + ((t + 1) & 1) * HPLANE;

    f32x4 a0a = {0.f,0.f,0.f,0.f}, a0b = {0.f,0.f,0.f,0.f};   // hi*hi (even/odd kt)
    f32x4 a1  = {0.f,0.f,0.f,0.f};                            // scale 2^-8
    f32x4 a2  = {0.f,0.f,0.f,0.f};                            // scale 2^-16

#define MFMA6(kt, ah, am, al)                                                \
    {                                                                        \
      u16x8 bh = *(const u16x8*)&lsBh[(kt) * 512 + lane * 8];                \
      u16x8 bm = *(const u16x8*)&lsBm[(kt) * 512 + lane * 8];                \
      u16x8 bl = *(const u16x8*)&lsBl[(kt) * 512 + lane * 8];                \
      f32x4& a0 = ((kt) & 1) ? a0b : a0a;                                    \
      a0 = __builtin_amdgcn_mfma_f32_16x16x32_bf16(asbf(ah), asbf(bh), a0, 0, 0, 0); \
      a1 = __builtin_amdgcn_mfma_f32_16x16x32_bf16(asbf(ah), asbf(bm), a1, 0, 0, 0); \
      a2 = __builtin_amdgcn_mfma_f32_16x16x32_bf16(asbf(ah), asbf(bl), a2, 0, 0, 0); \
      a1 = __builtin_amdgcn_mfma_f32_16x16x32_bf16(asbf(am), asbf(bh), a1, 0, 0, 0); \
      a2 = __builtin_amdgcn_mfma_f32_16x16x32_bf16(asbf(am), asbf(bm), a2, 0, 0, 0); \
      a2 = __builtin_amdgcn_mfma_f32_16x16x32_bf16(asbf(al), asbf(bh), a2, 0, 0, 0); \
    }
#define KTILE_H(kt, off)                                                     \
    {                                                                        \
      u16x8 ah = *(const u16x8*)&hrh[(off) + rowbase];                       \
      u16x8 am = *(const u16x8*)&hrm[(off) + rowbase];                       \
      u16x8 al = *(const u16x8*)&hrl[(off) + rowbase];                       \
      MFMA6(kt, ah, am, al)                                                  \
    }

    if (layer == 0) {
      // k-tiles 0..7: x_t fp32 -> exact 3-plane split in-register
      const float* xr = x + ((size_t)t * BATCH + arow) * IN_DIM + lk;
      #pragma unroll 4
      for (int kt = 0; kt < 8; ++kt) {
        float4 p0 = *(const float4*)(xr + kt * 32);
        float4 p1 = *(const float4*)(xr + kt * 32 + 4);
        float pv[8] = {p0.x, p0.y, p0.z, p0.w, p1.x, p1.y, p1.z, p1.w};
        u16x8 ah, am, al;
        #pragma unroll
        for (int i = 0; i < 8; ++i) {
          u16 h_, m_, l_;
          split3(pv[i], h_, m_, l_);
          ah[i] = h_; am[i] = m_; al[i] = l_;
        }
        MFMA6(kt, ah, am, al)
      }
      // k-tiles 8..23: h0 (Wrec0), 24..39: h1 (Wtd0)
      #pragma unroll 8
      for (int kt = 8; kt < 40; ++kt) {
        const int off = (kt < 24) ? (kt - 8) * 32 : BH + (kt - 24) * 32;
        KTILE_H(kt, off)
      }
    } else if (layer == 1) {
      // 0..15: h0 (Wbu1), 16..31: h1 (Wrec1), 32..47: h2 (Wtd1)
      #pragma unroll 8
      for (int kt = 0; kt < 48; ++kt) {
        const int off = (kt < 16) ? kt * 32
                      : (kt < 32) ? BH + (kt - 16) * 32
                                  : 2 * BH + (kt - 32) * 32;
        KTILE_H(kt, off)
      }
    } else {
      // 0..15: h1 (Wbu2), 16..31: h2 (Wrec2)
      #pragma unroll 8
      for (int kt = 0; kt < 32; ++kt) {
        const int off = (kt < 16) ? BH + kt * 32 : 2 * BH + (kt - 16) * 32;
        KTILE_H(kt, off)
      }
    }
#undef KTILE_H
#undef MFMA6

    // combine scale-separated accumulators (exact pow-2 scales)
    const f32x4 tot = (a0a + a0b) + a1 * (1.f / 256.f) + a2 * (1.f / 65536.f);

    // epilogue: bias + fp64 tanh, write exact 3-plane hidden (+ fp32 top for L2)
    // (nontemporal stores: keep L2 clean so the release wbl2 is cheap)
    {
      const int ncol  = c0 + (lane & 15);
      const int mbase = wv * 16 + ((lane >> 4) << 2);
      #pragma unroll
      for (int r = 0; r < 4; ++r) {
        const float h = (float)tanh((double)(tot[r] + bias));
        u16 h_, m_, l_;
        split3(h, h_, m_, l_);
        const int idx = (layer * BATCH + mbase + r) * HID + ncol;
        __builtin_nontemporal_store(h_, &hwh[idx]);
        __builtin_nontemporal_store(m_, &hwm[idx]);
        __builtin_nontemporal_store(l_, &hwl[idx]);
        if (layer == 2)
          __builtin_nontemporal_store(h, &top[((size_t)t * BATCH + mbase + r) * HID + ncol]);
      }
    }

    // device barrier: padded per-WG flags (parallel stores, no RMW chain)
    __syncthreads();
    if (tid == 0) {
      __threadfence();  // release: writeback XCD L2 so other XCDs see h
      __hip_atomic_store(&flags[(size_t)wg * 32], (unsigned)(t + 1),
                         __ATOMIC_RELAXED, __HIP_MEMORY_SCOPE_AGENT);
    }
    if (tid < NWG) {
      while (__hip_atomic_load(&flags[(size_t)tid * 32], __ATOMIC_RELAXED,
                               __HIP_MEMORY_SCOPE_AGENT) < (unsigned)(t + 1)) {
        __builtin_amdgcn_s_sleep(2);
      }
    }
    __syncthreads();
    if (tid == 0) __threadfence();  // acquire: invalidate stale L1/L2
    __syncthreads();
  }
}

// ---------------------------------------------------------------------------
// Epilogue: pred[t*64+m][128] = top[t*64+m][512] @ Wc[512][128] + bc
// (non-recurrent: plain-bf16 Wc error ~3e-4 << threshold)
// ---------------------------------------------------------------------------
__global__ __launch_bounds__(256, 1) void hrnn_pred(
    const float* __restrict__ top, const float* __restrict__ Wc,
    const float* __restrict__ bc, float* __restrict__ pred)
{
  __shared__ u16 lsW[OUT_DIM * HID];  // [c][k swizzled], 128 KB
  const int tid = threadIdx.x;
  for (int idx = tid; idx < OUT_DIM * HID; idx += 256) {
    const int k = idx >> 7, c = idx & 127;           // Wc row-major [512][128]
    const int kg = k >> 3, ko = k & 7;
    lsW[c * HID + (((kg ^ (c & 7)) << 3) + ko)] = f2bf(Wc[idx]);
  }
  __syncthreads();

  const int t = blockIdx.x;
  const int wv = tid >> 6, lane = tid & 63;
  const int lk = (lane >> 4) << 3;
  f32x4 acc[8];
  #pragma unroll
  for (int nt = 0; nt < 8; ++nt) acc[nt] = (f32x4){0.f, 0.f, 0.f, 0.f};

  const float* ar = top + ((size_t)t * BATCH + wv * 16 + (lane & 15)) * HID + lk;
  #pragma unroll 4
  for (int kt = 0; kt < 16; ++kt) {
    float4 p0 = *(const float4*)(ar + kt * 32);
    float4 p1 = *(const float4*)(ar + kt * 32 + 4);
    u16x8 av;
    av[0]=f2bf(p0.x); av[1]=f2bf(p0.y); av[2]=f2bf(p0.z); av[3]=f2bf(p0.w);
    av[4]=f2bf(p1.x); av[5]=f2bf(p1.y); av[6]=f2bf(p1.z); av[7]=f2bf(p1.w);
    const bf16x8 a = asbf(av);
    const int kg = kt * 4 + (lane >> 4);
    #pragma unroll
    for (int nt = 0; nt < 8; ++nt) {
      const int c = nt * 16 + (lane & 15);
      u16x8 bv = *(const u16x8*)&lsW[c * HID + ((kg ^ (lane & 7)) << 3)];
      acc[nt] = __builtin_amdgcn_mfma_f32_16x16x32_bf16(a, asbf(bv), acc[nt], 0, 0, 0);
    }
  }
  #pragma unroll
  for (int nt = 0; nt < 8; ++nt) {
    const int col = nt * 16 + (lane & 15);
    const float bcv = bc[col];
    #pragma unroll
    for (int r = 0; r < 4; ++r) {
      const int m = wv * 16 + ((lane >> 4) << 2) + r;
      pred[((size_t)t * BATCH + m) * OUT_DIM + col] = acc[nt][r] + bcv;
    }
  }
}

extern "C" void kernel_launch(void* const* d_in, const int* in_sizes, int n_in,
                              void* d_out, int out_size, void* d_ws, size_t ws_size,
                              hipStream_t stream) {
  const float* x     = (const float*)d_in[0];
  const float* Wbu0  = (const float*)d_in[1];
  const float* Wtd0  = (const float*)d_in[2];
  const float* Wrec0 = (const float*)d_in[3];
  const float* b0    = (const float*)d_in[4];
  const float* Wbu1  = (const float*)d_in[5];
  const float* Wtd1  = (const float*)d_in[6];
  const float* Wrec1 = (const float*)d_in[7];
  const float* b1    = (const float*)d_in[8];
  const float* Wbu2  = (const float*)d_in[9];
  const float* Wrec2 = (const float*)d_in[10];
  const float* b2    = (const float*)d_in[11];
  const float* Wc    = (const float*)d_in[12];
  const float* bc    = (const float*)d_in[13];

  float* pred = (float*)d_out;
  float* top  = pred + (size_t)T_STEPS * BATCH * OUT_DIM;

  const size_t FLAGS_BYTES  = 16384;                           // 96 x 128B padded
  const size_t planes_bytes = (size_t)6 * HPLANE * sizeof(u16); // 1.18 MB

  unsigned* flags;
  char* planes;
  if (ws_size >= FLAGS_BYTES + planes_bytes) {
    flags  = (unsigned*)d_ws;
    planes = (char*)d_ws + FLAGS_BYTES;
  } else if (ws_size >= FLAGS_BYTES) {
    flags  = (unsigned*)d_ws;
    planes = (char*)d_out;            // pred region; fully overwritten by hrnn_pred
  } else {
    flags  = (unsigned*)((char*)d_out + (8u << 20));  // inside pred region
    planes = (char*)d_out;
  }
  u16* hbh = (u16*)planes;
  u16* hbm = (u16*)(planes + 2 * HPLANE * sizeof(u16));
  u16* hbl = (u16*)(planes + 4 * HPLANE * sizeof(u16));

  // zero flags + all three ping-pong hidden planes (h_init = 0)
  hipMemsetAsync(flags, 0, FLAGS_BYTES, stream);
  hipMemsetAsync(planes, 0, planes_bytes, stream);

  hipLaunchKernelGGL(hrnn_persistent, dim3(NWG), dim3(256), 0, stream,
                     x, Wbu0, Wtd0, Wrec0, b0, Wbu1, Wtd1, Wrec1, b1,
                     Wbu2, Wrec2, b2, top, flags, hbh, hbm, hbl);
  hipLaunchKernelGGL(hrnn_pred, dim3(T_STEPS), dim3(256), 0, stream,
                     top, Wc, bc, pred);
}

// Round 7
// 11320.245 us; speedup vs baseline: 1.4734x; 1.3766x over previous
//
#include <hip/hip_runtime.h>
#include <hip/hip_bf16.h>
#include <math.h>

// SequentialHRNN: T=512, B=64, IN=256, H=512, OUT=128, 3 layers.
// EXACT-fp32-emulation persistent kernel (3-plane bf16 MFMA), r7:
// FENCE-FREE cross-XCD coherence. h state is stored write-through (sc0 sc1)
// and read L2-bypass (sc0 sc1) -> LLC is the serialization point; the two
// per-step __threadfence() (full-L2 wbl2 scans, ~20us/step hypothesis) are
// DELETED. Arithmetic bit-identical to r5/r6 (absmax must stay 0.05761719).

#define T_STEPS 512
#define BATCH   64
#define IN_DIM  256
#define HID     512
#define OUT_DIM 128
#define BH      (BATCH * HID)     // one layer plane: 32768 elems
#define HPLANE  (3 * BH)          // one ping-pong buffer (per precision plane)
#define NWG     96

typedef unsigned short u16;
typedef unsigned short u16x8 __attribute__((ext_vector_type(8)));
typedef __bf16 bf16x8 __attribute__((ext_vector_type(8)));
typedef float f32x4 __attribute__((ext_vector_type(4)));

static __device__ __forceinline__ u16 f2bf(float f) {
  unsigned u = __builtin_bit_cast(unsigned, f);
  u += 0x7fffu + ((u >> 16) & 1u);   // round-to-nearest-even
  return (u16)(u >> 16);
}
static __device__ __forceinline__ float bf2f(u16 h) {
  return __builtin_bit_cast(float, (unsigned)h << 16);
}
static __device__ __forceinline__ bf16x8 asbf(u16x8 v) {
  return __builtin_bit_cast(bf16x8, v);
}
// exact 3-way split: f == hi + mid*2^-8 + lo*2^-16 (all residuals exact)
static __device__ __forceinline__ void split3(float f, u16& hi, u16& mid, u16& lo) {
  hi = f2bf(f);
  const float r1 = f - bf2f(hi);
  mid = f2bf(r1 * 256.f);
  const float r2 = r1 - bf2f(mid) * (1.f / 256.f);
  lo = f2bf(r2 * 65536.f);
}

// ---------------------------------------------------------------------------
// Grid: 96 blocks x 256 threads. Block wg: layer = wg>>5, c0 = (wg&31)*16.
// Wave wv (of 4) = M-tile (rows wv*16..+16); all waves share the 16 cols.
// LDS: weight slice in 3 bf16 planes, MFMA B-frag layout (147 KB), staged once.
// concat-K maps: L0: [x->Wbu0(256) | h0->Wrec0 | h1->Wtd0]   KT=40
//                L1: [h0->Wbu1 | h1->Wrec1 | h2->Wtd1]       KT=48
//                L2: [h1->Wbu2 | h2->Wrec2]                  KT=32
// Barrier: per-WG padded flags (LLC); NO fences (h traffic is LLC-coherent).
// ---------------------------------------------------------------------------
__global__ __launch_bounds__(256, 1) void hrnn_persistent(
    const float* __restrict__ x,
    const float* __restrict__ Wbu0, const float* __restrict__ Wtd0,
    const float* __restrict__ Wrec0, const float* __restrict__ b0,
    const float* __restrict__ Wbu1, const float* __restrict__ Wtd1,
    const float* __restrict__ Wrec1, const float* __restrict__ b1,
    const float* __restrict__ Wbu2, const float* __restrict__ Wrec2,
    const float* __restrict__ b2,
    float* __restrict__ top,        // [T][64][512] fp32 (d_out region 2)
    unsigned* __restrict__ flags,   // 96 x 32 u32 padded flags (zeroed)
    u16* __restrict__ hbh,          // [2][3][64][512] bf16 hi plane (zeroed)
    u16* __restrict__ hbm,          // mid plane (x 2^8)
    u16* __restrict__ hbl)          // lo plane (x 2^16)
{
  __shared__ u16 lsBh[48 * 512];    // B-frag hi: lsBh[kt*512 + lane*8 + i]
  __shared__ u16 lsBm[48 * 512];    // B-frag mid (x 2^8)
  __shared__ u16 lsBl[48 * 512];    // B-frag lo  (x 2^16)

  const int wg    = blockIdx.x;
  const int layer = wg >> 5;
  const int c0    = (wg & 31) * 16;       // column base within layer
  const int tid   = threadIdx.x;
  const int wv    = tid >> 6;             // M-tile index 0..3
  const int lane  = tid & 63;
  const int KT    = (layer == 0) ? 40 : ((layer == 1) ? 48 : 32);

  // ---- one-time: stage weight slice (3 planes) into LDS, B-frag layout ----
  {
    const int cc = c0 + (lane & 15);
    for (int f = wv; f < KT; f += 4) {
      const int kk = f * 32 + ((lane >> 4) << 3);  // concat-k of first of 8
      const float* Wsrc; int kloc;
      if (layer == 0) {
        if (kk < 256)      { Wsrc = Wbu0;  kloc = kk; }
        else if (kk < 768) { Wsrc = Wrec0; kloc = kk - 256; }
        else               { Wsrc = Wtd0;  kloc = kk - 768; }
      } else if (layer == 1) {
        if (kk < 512)       { Wsrc = Wbu1;  kloc = kk; }
        else if (kk < 1024) { Wsrc = Wrec1; kloc = kk - 512; }
        else                { Wsrc = Wtd1;  kloc = kk - 1024; }
      } else {
        if (kk < 512) { Wsrc = Wbu2;  kloc = kk; }
        else          { Wsrc = Wrec2; kloc = kk - 512; }
      }
      u16* dh = &lsBh[f * 512 + lane * 8];
      u16* dm = &lsBm[f * 512 + lane * 8];
      u16* dl = &lsBl[f * 512 + lane * 8];
      #pragma unroll
      for (int i = 0; i < 8; ++i) {
        u16 h_, m_, l_;
        split3(Wsrc[(size_t)(kloc + i) * HID + cc], h_, m_, l_);
        dh[i] = h_; dm[i] = m_; dl[i] = l_;
      }
    }
  }
  const float* bl_ = (layer == 0) ? b0 : ((layer == 1) ? b1 : b2);
  const float bias = bl_[c0 + (lane & 15)];
  __syncthreads();

  const int arow    = wv * 16 + (lane & 15);   // A-operand batch row (0..63)
  const int lk      = (lane >> 4) << 3;        // A-operand k sub-offset
  const int rowbase = arow * HID + lk;

  for (int t = 0; t < T_STEPS; ++t) {
    const u16* hrh = hbh + (t & 1) * HPLANE;
    const u16* hrm = hbm + (t & 1) * HPLANE;
    const u16* hrl = hbl + (t & 1) * HPLANE;
    u16* hwh       = hbh + ((t + 1) & 1) * HPLANE;
    u16* hwm       = hbm + ((t + 1) & 1) * HPLANE;
    u16* hwl       = hbl + ((t + 1) & 1) * HPLANE;

    f32x4 a0a = {0.f,0.f,0.f,0.f}, a0b = {0.f,0.f,0.f,0.f};   // hi*hi (even/odd kt)
    f32x4 a1  = {0.f,0.f,0.f,0.f};                            // scale 2^-8
    f32x4 a2  = {0.f,0.f,0.f,0.f};                            // scale 2^-16

#define MFMA6(kt, ah, am, al)                                                \
    {                                                                        \
      u16x8 bh = *(const u16x8*)&lsBh[(kt) * 512 + lane * 8];                \
      u16x8 bm = *(const u16x8*)&lsBm[(kt) * 512 + lane * 8];                \
      u16x8 bl = *(const u16x8*)&lsBl[(kt) * 512 + lane * 8];                \
      f32x4& a0 = ((kt) & 1) ? a0b : a0a;                                    \
      a0 = __builtin_amdgcn_mfma_f32_16x16x32_bf16(asbf(ah), asbf(bh), a0, 0, 0, 0); \
      a1 = __builtin_amdgcn_mfma_f32_16x16x32_bf16(asbf(ah), asbf(bm), a1, 0, 0, 0); \
      a2 = __builtin_amdgcn_mfma_f32_16x16x32_bf16(asbf(ah), asbf(bl), a2, 0, 0, 0); \
      a1 = __builtin_amdgcn_mfma_f32_16x16x32_bf16(asbf(am), asbf(bh), a1, 0, 0, 0); \
      a2 = __builtin_amdgcn_mfma_f32_16x16x32_bf16(asbf(am), asbf(bm), a2, 0, 0, 0); \
      a2 = __builtin_amdgcn_mfma_f32_16x16x32_bf16(asbf(al), asbf(bh), a2, 0, 0, 0); \
    }

// Coherent (L2-bypass) h-tile load: LLC read, no acquire fence needed.
#define LOAD_TILE(i, off_)                                                   \
    { const int o_ = (off_) + rowbase;                                       \
      const u16* pa_ = &hrh[o_]; const u16* pm_ = &hrm[o_];                  \
      const u16* pl_ = &hrl[o_];                                             \
      asm volatile("global_load_dwordx4 %0, %1, off sc0 sc1 nt"              \
                   : "=v"(Ah[i]) : "v"(pa_));                                \
      asm volatile("global_load_dwordx4 %0, %1, off sc0 sc1 nt"              \
                   : "=v"(Am[i]) : "v"(pm_));                                \
      asm volatile("global_load_dwordx4 %0, %1, off sc0 sc1 nt"              \
                   : "=v"(Al[i]) : "v"(pl_)); }

// One chunk of 8 h k-tiles: 24 loads in flight -> drain -> 48 MFMAs.
#define H_CHUNK8(kt0, cbase)                                                 \
    {                                                                        \
      u16x8 Ah[8], Am[8], Al[8];                                             \
      _Pragma("unroll")                                                      \
      for (int i = 0; i < 8; ++i) LOAD_TILE(i, (cbase) + i * 32)             \
      asm volatile("s_waitcnt vmcnt(0)" ::: "memory");                       \
      __builtin_amdgcn_sched_barrier(0);                                     \
      _Pragma("unroll")                                                      \
      for (int i = 0; i < 8; ++i) MFMA6((kt0) + i, Ah[i], Am[i], Al[i])      \
    }

    if (layer == 0) {
      // k-tiles 0..7: x_t fp32 -> exact 3-plane split in-register (cached loads)
      const float* xr = x + ((size_t)t * BATCH + arow) * IN_DIM + lk;
      #pragma unroll 4
      for (int kt = 0; kt < 8; ++kt) {
        float4 p0 = *(const float4*)(xr + kt * 32);
        float4 p1 = *(const float4*)(xr + kt * 32 + 4);
        float pv[8] = {p0.x, p0.y, p0.z, p0.w, p1.x, p1.y, p1.z, p1.w};
        u16x8 ah, am, al;
        #pragma unroll
        for (int i = 0; i < 8; ++i) {
          u16 h_, m_, l_;
          split3(pv[i], h_, m_, l_);
          ah[i] = h_; am[i] = m_; al[i] = l_;
        }
        MFMA6(kt, ah, am, al)
      }
      // k-tiles 8..23: h0 (Wrec0), 24..39: h1 (Wtd0)
      H_CHUNK8(8,  0)
      H_CHUNK8(16, 8 * 32)
      H_CHUNK8(24, BH)
      H_CHUNK8(32, BH + 8 * 32)
    } else if (layer == 1) {
      // 0..15: h0 (Wbu1), 16..31: h1 (Wrec1), 32..47: h2 (Wtd1)
      H_CHUNK8(0,  0)
      H_CHUNK8(8,  8 * 32)
      H_CHUNK8(16, BH)
      H_CHUNK8(24, BH + 8 * 32)
      H_CHUNK8(32, 2 * BH)
      H_CHUNK8(40, 2 * BH + 8 * 32)
    } else {
      // 0..15: h1 (Wbu2), 16..31: h2 (Wrec2)
      H_CHUNK8(0,  BH)
      H_CHUNK8(8,  BH + 8 * 32)
      H_CHUNK8(16, 2 * BH)
      H_CHUNK8(24, 2 * BH + 8 * 32)
    }
#undef H_CHUNK8
#undef LOAD_TILE
#undef MFMA6

    // combine scale-separated accumulators (exact pow-2 scales)
    const f32x4 tot = (a0a + a0b) + a1 * (1.f / 256.f) + a2 * (1.f / 65536.f);

    // epilogue: bias + fp64 tanh; h written WRITE-THROUGH (sc0 sc1) so L2
    // never holds dirty recurrent state -> no release wbl2 needed.
#define ST16(p, v) asm volatile("global_store_short %0, %1, off sc0 sc1 nt" \
                                :: "v"(p), "v"(v) : "memory")
    {
      const int ncol  = c0 + (lane & 15);
      const int mbase = wv * 16 + ((lane >> 4) << 2);
      #pragma unroll
      for (int r = 0; r < 4; ++r) {
        const float h = (float)tanh((double)(tot[r] + bias));
        u16 h_, m_, l_;
        split3(h, h_, m_, l_);
        const int idx = (layer * BATCH + mbase + r) * HID + ncol;
        ST16(&hwh[idx], h_);
        ST16(&hwm[idx], m_);
        ST16(&hwl[idx], l_);
        if (layer == 2)
          __builtin_nontemporal_store(h, &top[((size_t)t * BATCH + mbase + r) * HID + ncol]);
      }
    }
#undef ST16

    // drain this wave's h stores to LLC, then barrier via padded flags.
    asm volatile("s_waitcnt vmcnt(0)" ::: "memory");
    __builtin_amdgcn_sched_barrier(0);
    __syncthreads();
    if (tid == 0) {
      __hip_atomic_store(&flags[(size_t)wg * 32], (unsigned)(t + 1),
                         __ATOMIC_RELAXED, __HIP_MEMORY_SCOPE_AGENT);
    }
    if (tid < NWG) {
      while (__hip_atomic_load(&flags[(size_t)tid * 32], __ATOMIC_RELAXED,
                               __HIP_MEMORY_SCOPE_AGENT) < (unsigned)(t + 1)) {
        __builtin_amdgcn_s_sleep(2);
      }
    }
    __syncthreads();
  }
}

// ---------------------------------------------------------------------------
// Epilogue: pred[t*64+m][128] = top[t*64+m][512] @ Wc[512][128] + bc
// (non-recurrent: plain-bf16 Wc error ~3e-4 << threshold)
// ---------------------------------------------------------------------------
__global__ __launch_bounds__(256, 1) void hrnn_pred(
    const float* __restrict__ top, const float* __restrict__ Wc,
    const float* __restrict__ bc, float* __restrict__ pred)
{
  __shared__ u16 lsW[OUT_DIM * HID];  // [c][k swizzled], 128 KB
  const int tid = threadIdx.x;
  for (int idx = tid; idx < OUT_DIM * HID; idx += 256) {
    const int k = idx >> 7, c = idx & 127;           // Wc row-major [512][128]
    const int kg = k >> 3, ko = k & 7;
    lsW[c * HID + (((kg ^ (c & 7)) << 3) + ko)] = f2bf(Wc[idx]);
  }
  __syncthreads();

  const int t = blockIdx.x;
  const int wv = tid >> 6, lane = tid & 63;
  const int lk = (lane >> 4) << 3;
  f32x4 acc[8];
  #pragma unroll
  for (int nt = 0; nt < 8; ++nt) acc[nt] = (f32x4){0.f, 0.f, 0.f, 0.f};

  const float* ar = top + ((size_t)t * BATCH + wv * 16 + (lane & 15)) * HID + lk;
  #pragma unroll 4
  for (int kt = 0; kt < 16; ++kt) {
    float4 p0 = *(const float4*)(ar + kt * 32);
    float4 p1 = *(const float4*)(ar + kt * 32 + 4);
    u16x8 av;
    av[0]=f2bf(p0.x); av[1]=f2bf(p0.y); av[2]=f2bf(p0.z); av[3]=f2bf(p0.w);
    av[4]=f2bf(p1.x); av[5]=f2bf(p1.y); av[6]=f2bf(p1.z); av[7]=f2bf(p1.w);
    const bf16x8 a = asbf(av);
    const int kg = kt * 4 + (lane >> 4);
    #pragma unroll
    for (int nt = 0; nt < 8; ++nt) {
      const int c = nt * 16 + (lane & 15);
      u16x8 bv = *(const u16x8*)&lsW[c * HID + ((kg ^ (lane & 7)) << 3)];
      acc[nt] = __builtin_amdgcn_mfma_f32_16x16x32_bf16(a, asbf(bv), acc[nt], 0, 0, 0);
    }
  }
  #pragma unroll
  for (int nt = 0; nt < 8; ++nt) {
    const int col = nt * 16 + (lane & 15);
    const float bcv = bc[col];
    #pragma unroll
    for (int r = 0; r < 4; ++r) {
      const int m = wv * 16 + ((lane >> 4) << 2) + r;
      pred[((size_t)t * BATCH + m) * OUT_DIM + col] = acc[nt][r] + bcv;
    }
  }
}

extern "C" void kernel_launch(void* const* d_in, const int* in_sizes, int n_in,
                              void* d_out, int out_size, void* d_ws, size_t ws_size,
                              hipStream_t stream) {
  const float* x     = (const float*)d_in[0];
  const float* Wbu0  = (const float*)d_in[1];
  const float* Wtd0  = (const float*)d_in[2];
  const float* Wrec0 = (const float*)d_in[3];
  const float* b0    = (const float*)d_in[4];
  const float* Wbu1  = (const float*)d_in[5];
  const float* Wtd1  = (const float*)d_in[6];
  const float* Wrec1 = (const float*)d_in[7];
  const float* b1    = (const float*)d_in[8];
  const float* Wbu2  = (const float*)d_in[9];
  const float* Wrec2 = (const float*)d_in[10];
  const float* b2    = (const float*)d_in[11];
  const float* Wc    = (const float*)d_in[12];
  const float* bc    = (const float*)d_in[13];

  float* pred = (float*)d_out;
  float* top  = pred + (size_t)T_STEPS * BATCH * OUT_DIM;

  const size_t FLAGS_BYTES  = 16384;                            // 96 x 128B padded
  const size_t planes_bytes = (size_t)6 * HPLANE * sizeof(u16); // 1.18 MB

  unsigned* flags;
  char* planes;
  if (ws_size >= FLAGS_BYTES + planes_bytes) {
    flags  = (unsigned*)d_ws;
    planes = (char*)d_ws + FLAGS_BYTES;
  } else if (ws_size >= FLAGS_BYTES) {
    flags  = (unsigned*)d_ws;
    planes = (char*)d_out;            // pred region; fully overwritten by hrnn_pred
  } else {
    flags  = (unsigned*)((char*)d_out + (8u << 20));  // inside pred region
    planes = (char*)d_out;
  }
  u16* hbh = (u16*)planes;
  u16* hbm = (u16*)(planes + 2 * HPLANE * sizeof(u16));
  u16* hbl = (u16*)(planes + 4 * HPLANE * sizeof(u16));

  // zero flags + all three ping-pong hidden planes (h_init = 0)
  hipMemsetAsync(flags, 0, FLAGS_BYTES, stream);
  hipMemsetAsync(planes, 0, planes_bytes, stream);

  hipLaunchKernelGGL(hrnn_persistent, dim3(NWG), dim3(256), 0, stream,
                     x, Wbu0, Wtd0, Wrec0, b0, Wbu1, Wtd1, Wrec1, b1,
                     Wbu2, Wrec2, b2, top, flags, hbh, hbm, hbl);
  hipLaunchKernelGGL(hrnn_pred, dim3(T_STEPS), dim3(256), 0, stream,
                     top, Wc, bc, pred);
}